// Round 4
// baseline (128.127 us; speedup 1.0000x reference)
//
#include <hip/hip_runtime.h>

#define B_ 128
#define O_ 1024
#define I_ 1024
#define NCHUNK 64
#define CI (I_ / NCHUNK)     // 16 i-values per wave
#define WPB 4                // waves per block
#define NOB (O_ / 32)        // 32 o-blocks in build_T2 grid (min partials)
#define TT_BYTES ((size_t)O_ * I_ * sizeof(float))

#define LOG2E_F  1.4426950408889634f
#define LN2_F    0.6931471805599453f
#define LN2SQ_F  0.4804530139182014f          // ln2^2
#define EPSC_F   (1e-7f * LN2SQ_F)            // eps * ln2^2

typedef float v2f __attribute__((ext_vector_type(2)));

__device__ __forceinline__ float fast_rsq(float x)  { return __builtin_amdgcn_rsqf(x); }
__device__ __forceinline__ float fast_exp2(float x) { return __builtin_amdgcn_exp2f(x); }
__device__ __forceinline__ float fast_rcp(float x)  { return __builtin_amdgcn_rcpf(x); }

__device__ __forceinline__ float readlane_f(float x, int l) {
    return __builtin_bit_cast(float,
        __builtin_amdgcn_readlane(__builtin_bit_cast(int, x), l));
}

// DPP add step (ctrl must be an immediate -> template param);
// bound_ctrl=true: invalid sources read 0.
template <int CTRL>
__device__ __forceinline__ float dpp_add(float v) {
    int x = __builtin_amdgcn_update_dpp(0, __builtin_bit_cast(int, v),
                                        CTRL, 0xf, 0xf, true);
    return v + __builtin_bit_cast(float, x);
}
// 64-lane sum; total lands in lane 63, returned as SGPR-uniform float.
__device__ __forceinline__ float wave_sum_uniform(float v) {
    v = dpp_add<0xB1>(v);   // quad_perm [1,0,3,2] : pair sums
    v = dpp_add<0x4E>(v);   // quad_perm [2,3,0,1] : quad sums
    v = dpp_add<0x141>(v);  // row_half_mirror     : octet sums
    v = dpp_add<0x140>(v);  // row_mirror          : row-of-16 sums
    v = dpp_add<0x142>(v);  // row_bcast15         : rows 1..3 += prev row
    v = dpp_add<0x143>(v);  // row_bcast31         : rows 2,3 += rows 0+1
    return __builtin_bit_cast(float,
        __builtin_amdgcn_readlane(__builtin_bit_cast(int, v), 63));
}

// ---------------------------------------------------------------------------
// Fused kernel 1: Tt2[i*O+o] = T[o,i]^2 (transposed+squared), plus
//  - per-(i, o-block) min written RACE-FREE to minpart[i][ob] (no global
//    atomics, no init memset dispatch; aeg reduces the 32 partials per i),
//  - zeroing of d_out (1024 blocks x 128 elems = 131072 = B*O).
// ---------------------------------------------------------------------------
__global__ __launch_bounds__(256) void build_T2_kernel(
    const float* __restrict__ ix, const float* __restrict__ iy,
    const float* __restrict__ ox, const float* __restrict__ oy,
    const float* __restrict__ la, const float* __restrict__ lm,
    float* __restrict__ Tt2, unsigned* __restrict__ minpart,
    float* __restrict__ out_zero)
{
    __shared__ float tile[32][33];
    __shared__ unsigned mloc[32];
    const int i0 = blockIdx.x * 32;
    const int o0 = blockIdx.y * 32;
    const int tx = threadIdx.x;      // 0..31
    const int ty = threadIdx.y;      // 0..7
    const int t  = ty * 32 + tx;     // 0..255

    if (t < 32) mloc[t] = 0xFFFFFFFFu;

    // fold the d_out zeroing in (saves a memset dispatch)
    const int bid = blockIdx.y * gridDim.x + blockIdx.x;   // 0..1023
    if (t < 128) out_zero[bid * 128 + t] = 0.0f;

#pragma unroll
    for (int r = 0; r < 32; r += 8) {
        const int o = o0 + ty + r;
        const int i = i0 + tx;
        const int idx = o * I_ + i;
        const float tt = fmaf(ix[idx] * fast_rcp(iy[idx]) + la[idx],
                              1.0f + lm[idx],
                              -(ox[idx] * fast_rcp(oy[idx])));
        tile[ty + r][tx] = tt * tt;
    }
    __syncthreads();
#pragma unroll
    for (int r = 0; r < 32; r += 8) {
        Tt2[(i0 + ty + r) * O_ + o0 + tx] = tile[tx][ty + r];
    }
    // per-i min over this block's 32 o's: thread t covers i_local=t&31,
    // o_locals = (t>>5)*4 .. +3  (uint-bit min valid: r2 >= 0)
    const int il = t & 31;
    const int g  = t >> 5;
    float mn = fminf(fminf(tile[4 * g + 0][il], tile[4 * g + 1][il]),
                     fminf(tile[4 * g + 2][il], tile[4 * g + 3][il]));
    atomicMin(&mloc[il], __builtin_bit_cast(unsigned, mn));
    __syncthreads();
    if (t < 32) minpart[(size_t)(i0 + t) * NOB + blockIdx.y] = mloc[t];
}

// ---------------------------------------------------------------------------
// Kernel 2: wave owns chunk of 16 i's and TWO batch rows (b0, b1); lane owns
// 16 o's. The two b-streams share the Tt2 row loads (halves L2 traffic) and
// are mutually independent, so stream B's rsq/exp2 issue fills stream A's
// serial z-reduce tail (measured 38k bubble cycles/SIMD in the 1-stream
// version). __launch_bounds__(256,4) caps VGPR at 128 (est. need ~105;
// forcing 64 in R2 spilled catastrophically — don't go below 4 waves).
// Prologue: reduce 32 min-partials per i; lane groups derive per-(b,i)
// sigmoid values in parallel, readlane -> SGPR at use sites.
// ---------------------------------------------------------------------------
__global__ __launch_bounds__(256, 4) void aeg_main_kernel(
    const float* __restrict__ data,   // (B, I)
    const float* __restrict__ Tt2,    // (I, O) transposed T^2
    const float* __restrict__ minpart,// (I, NOB) min partials (float bits)
    float* __restrict__ out)          // (B, O), zeroed by build_T2
{
    __shared__ float red[2][WPB][O_];    // 32 KB

    const int w    = threadIdx.x >> 6;
    const int lane = threadIdx.x & 63;
    const int chunk = blockIdx.x * WPB + w;
    const int b0    = 2 * blockIdx.y;

    const float4* rowbase = (const float4*)(Tt2 + (size_t)chunk * CI * O_);

    // ---- prologue ----
    const int li = lane & 15;
    const int whichb = (lane >> 4) & 1;   // lanes 0-15:b0, 16-31:b1 (32+ dup)

    // exact min over the 32 o-block partials for i = chunk*CI + li
    const float4* mp4 = (const float4*)(minpart + (size_t)(chunk * CI + li) * NOB);
    float4 m0 = mp4[0], m1 = mp4[1], m2_ = mp4[2], m3 = mp4[3];
    float4 m4 = mp4[4], m5 = mp4[5], m6 = mp4[6], m7 = mp4[7];
    float mra = fminf(
        fminf(fminf(fminf(m0.x, m0.y), fminf(m0.z, m0.w)),
              fminf(fminf(m1.x, m1.y), fminf(m1.z, m1.w))),
        fminf(fminf(fminf(m2_.x, m2_.y), fminf(m2_.z, m2_.w)),
              fminf(fminf(m3.x, m3.y), fminf(m3.z, m3.w))));
    float mrb = fminf(
        fminf(fminf(fminf(m4.x, m4.y), fminf(m4.z, m4.w)),
              fminf(fminf(m5.x, m5.y), fminf(m5.z, m5.w))),
        fminf(fminf(fminf(m6.x, m6.y), fminf(m6.z, m6.w)),
              fminf(fminf(m7.x, m7.y), fminf(m7.z, m7.w))));
    const float mr_l = fminf(mra, mrb);

    // per-(b,i) sigmoid-derived values; lane group picks its b
    const float dv_l  = data[(b0 + whichb) * I_ + chunk * CI + li];
    const float sig_l = fast_rcp(1.0f + fast_exp2(-dv_l * LOG2E_F));
    const float sc_l  = sig_l * LN2_F;
    const float s2_l  = sc_l * sc_l;
    const float m2_l  = fast_rsq(fmaf(mr_l, s2_l, EPSC_F)); // exact max (log2 units)

    v2f acca[8], accb[8];
#pragma unroll
    for (int j = 0; j < 8; ++j) { acca[j] = (v2f)0.0f; accb[j] = (v2f)0.0f; }

#pragma unroll
    for (int ii = 0; ii < CI; ++ii) {
        const float4* r4 = rowbase + (size_t)ii * (O_ / 4);
        float4 rr[4];
#pragma unroll
        for (int k = 0; k < 4; ++k) rr[k] = r4[lane + 64 * k];

        const float s2af = readlane_f(s2_l, ii);
        const float m2af = readlane_f(m2_l, ii);
        const float s2bf = readlane_f(s2_l, 16 + ii);
        const float m2bf = readlane_f(m2_l, 16 + ii);
        const v2f s2a = {s2af, s2af}, m2a = {m2af, m2af};
        const v2f s2b = {s2bf, s2bf}, m2b = {m2bf, m2bf};
        const v2f epv = {EPSC_F, EPSC_F};

        v2f ea[8], eb[8];
        v2f za0 = (v2f)0.0f, za1 = (v2f)0.0f;
        v2f zb0 = (v2f)0.0f, zb1 = (v2f)0.0f;
#pragma unroll
        for (int k = 0; k < 4; ++k) {
            const v2f x0 = {rr[k].x, rr[k].y};
            const v2f x1 = {rr[k].z, rr[k].w};
            // stream A (b0)
            const v2f qa0 = x0 * s2a + epv;
            const v2f qa1 = x1 * s2a + epv;
            v2f ta0, ta1;
            ta0.x = fast_rsq(qa0.x); ta0.y = fast_rsq(qa0.y);
            ta1.x = fast_rsq(qa1.x); ta1.y = fast_rsq(qa1.y);
            ta0 -= m2a; ta1 -= m2a;
            v2f ev0, ev1;
            ev0.x = fast_exp2(ta0.x); ev0.y = fast_exp2(ta0.y);
            ev1.x = fast_exp2(ta1.x); ev1.y = fast_exp2(ta1.y);
            ea[2 * k] = ev0; ea[2 * k + 1] = ev1;
            za0 += ev0; za1 += ev1;
            // stream B (b1)
            const v2f qb0 = x0 * s2b + epv;
            const v2f qb1 = x1 * s2b + epv;
            v2f tb0, tb1;
            tb0.x = fast_rsq(qb0.x); tb0.y = fast_rsq(qb0.y);
            tb1.x = fast_rsq(qb1.x); tb1.y = fast_rsq(qb1.y);
            tb0 -= m2b; tb1 -= m2b;
            v2f fv0, fv1;
            fv0.x = fast_exp2(tb0.x); fv0.y = fast_exp2(tb0.y);
            fv1.x = fast_exp2(tb1.x); fv1.y = fast_exp2(tb1.y);
            eb[2 * k] = fv0; eb[2 * k + 1] = fv1;
            zb0 += fv0; zb1 += fv1;
        }
        const v2f za = za0 + za1;
        const v2f zb = zb0 + zb1;
        const float zta = wave_sum_uniform(za.x + za.y);   // SGPR-uniform
        const float ztb = wave_sum_uniform(zb.x + zb.y);
        const float sa = readlane_f(dv_l, ii)      * fast_rcp(zta);  // z >= 1
        const float sb = readlane_f(dv_l, 16 + ii) * fast_rcp(ztb);
        const v2f sav = {sa, sa}, sbv = {sb, sb};
#pragma unroll
        for (int j = 0; j < 8; ++j) {
            acca[j] = ea[j] * sav + acca[j];
            accb[j] = eb[j] * sbv + accb[j];
        }
    }

    // Stage per-wave accumulators, reduce across the 4 waves in LDS.
#pragma unroll
    for (int k = 0; k < 4; ++k) {
        float4 va, vb;
        va.x = acca[2 * k].x;     va.y = acca[2 * k].y;
        va.z = acca[2 * k + 1].x; va.w = acca[2 * k + 1].y;
        vb.x = accb[2 * k].x;     vb.y = accb[2 * k].y;
        vb.z = accb[2 * k + 1].x; vb.w = accb[2 * k + 1].y;
        ((float4*)&red[0][w][256 * k])[lane] = va;
        ((float4*)&red[1][w][256 * k])[lane] = vb;
    }
    __syncthreads();

    const int t = threadIdx.x;
#pragma unroll
    for (int s = 0; s < 2; ++s) {
        float4 v = ((const float4*)red[s][0])[t];
#pragma unroll
        for (int ww = 1; ww < WPB; ++ww) {
            const float4 u = ((const float4*)red[s][ww])[t];
            v.x += u.x; v.y += u.y; v.z += u.z; v.w += u.w;
        }
        float* ob = out + (size_t)(b0 + s) * O_ + 4 * t;
        atomicAdd(&ob[0], v.x);
        atomicAdd(&ob[1], v.y);
        atomicAdd(&ob[2], v.z);
        atomicAdd(&ob[3], v.w);
    }
}

// ---------------------------------------------------------------------------
extern "C" void kernel_launch(void* const* d_in, const int* in_sizes, int n_in,
                              void* d_out, int out_size, void* d_ws, size_t ws_size,
                              hipStream_t stream)
{
    const float* data = (const float*)d_in[0];
    const float* ix   = (const float*)d_in[1];
    const float* iy   = (const float*)d_in[2];
    const float* ox   = (const float*)d_in[3];
    const float* oy   = (const float*)d_in[4];
    const float* la   = (const float*)d_in[5];
    const float* lm   = (const float*)d_in[6];
    float* out  = (float*)d_out;
    float* Tt2  = (float*)d_ws;
    unsigned* minpart = (unsigned*)((char*)d_ws + TT_BYTES);

    build_T2_kernel<<<dim3(I_ / 32, O_ / 32), dim3(32, 8), 0, stream>>>(
        ix, iy, ox, oy, la, lm, Tt2, minpart, out);

    aeg_main_kernel<<<dim3(NCHUNK / WPB, B_ / 2), 256, 0, stream>>>(
        data, Tt2, (const float*)minpart, out);
}

// Round 6
// 122.769 us; speedup vs baseline: 1.0436x; 1.0436x over previous
//
#include <hip/hip_runtime.h>

#define B_ 128
#define O_ 1024
#define I_ 1024
#define NCHUNK 64
#define CI (I_ / NCHUNK)     // 16 i-values per wave
#define WPB 4                // waves per block
#define NOB (O_ / 32)        // 32 o-blocks in build_T2 grid (min partials)
#define TT_BYTES ((size_t)O_ * I_ * sizeof(float))

#define LOG2E_F  1.4426950408889634f
#define LN2_F    0.6931471805599453f
#define LN2SQ_F  0.4804530139182014f          // ln2^2
#define EPSC_F   (1e-7f * LN2SQ_F)            // eps * ln2^2

typedef float v2f __attribute__((ext_vector_type(2)));

__device__ __forceinline__ float fast_rsq(float x)  { return __builtin_amdgcn_rsqf(x); }
__device__ __forceinline__ float fast_exp2(float x) { return __builtin_amdgcn_exp2f(x); }
__device__ __forceinline__ float fast_rcp(float x)  { return __builtin_amdgcn_rcpf(x); }

__device__ __forceinline__ float readlane_f(float x, int l) {
    return __builtin_bit_cast(float,
        __builtin_amdgcn_readlane(__builtin_bit_cast(int, x), l));
}

// DPP add step (ctrl must be an immediate -> template param);
// bound_ctrl=true: invalid sources read 0.
template <int CTRL>
__device__ __forceinline__ float dpp_add(float v) {
    int x = __builtin_amdgcn_update_dpp(0, __builtin_bit_cast(int, v),
                                        CTRL, 0xf, 0xf, true);
    return v + __builtin_bit_cast(float, x);
}
// 64-lane sum; total lands in lane 63, returned as SGPR-uniform float.
__device__ __forceinline__ float wave_sum_uniform(float v) {
    v = dpp_add<0xB1>(v);   // quad_perm [1,0,3,2] : pair sums
    v = dpp_add<0x4E>(v);   // quad_perm [2,3,0,1] : quad sums
    v = dpp_add<0x141>(v);  // row_half_mirror     : octet sums
    v = dpp_add<0x140>(v);  // row_mirror          : row-of-16 sums
    v = dpp_add<0x142>(v);  // row_bcast15         : rows 1..3 += prev row
    v = dpp_add<0x143>(v);  // row_bcast31         : rows 2,3 += rows 0+1
    return __builtin_bit_cast(float,
        __builtin_amdgcn_readlane(__builtin_bit_cast(int, v), 63));
}

// ---------------------------------------------------------------------------
// Fused kernel 1: Tt2[i*O+o] = T[o,i]^2 (transposed+squared), plus
//  - per-(i, o-block) min written RACE-FREE to minpart[i][ob] (no global
//    atomics, no init-memset dispatch; aeg reduces the 32 partials per i),
//  - zeroing of d_out (1024 blocks x 128 elems = 131072 = B*O).
// (This exact kernel passed in R4.)
// ---------------------------------------------------------------------------
__global__ __launch_bounds__(256) void build_T2_kernel(
    const float* __restrict__ ix, const float* __restrict__ iy,
    const float* __restrict__ ox, const float* __restrict__ oy,
    const float* __restrict__ la, const float* __restrict__ lm,
    float* __restrict__ Tt2, unsigned* __restrict__ minpart,
    float* __restrict__ out_zero)
{
    __shared__ float tile[32][33];
    __shared__ unsigned mloc[32];
    const int i0 = blockIdx.x * 32;
    const int o0 = blockIdx.y * 32;
    const int tx = threadIdx.x;      // 0..31
    const int ty = threadIdx.y;      // 0..7
    const int t  = ty * 32 + tx;     // 0..255

    if (t < 32) mloc[t] = 0xFFFFFFFFu;

    // fold the d_out zeroing in (saves a memset dispatch)
    const int bid = blockIdx.y * gridDim.x + blockIdx.x;   // 0..1023
    if (t < 128) out_zero[bid * 128 + t] = 0.0f;

#pragma unroll
    for (int r = 0; r < 32; r += 8) {
        const int o = o0 + ty + r;
        const int i = i0 + tx;
        const int idx = o * I_ + i;
        const float tt = fmaf(ix[idx] * fast_rcp(iy[idx]) + la[idx],
                              1.0f + lm[idx],
                              -(ox[idx] * fast_rcp(oy[idx])));
        tile[ty + r][tx] = tt * tt;
    }
    __syncthreads();
#pragma unroll
    for (int r = 0; r < 32; r += 8) {
        Tt2[(i0 + ty + r) * O_ + o0 + tx] = tile[tx][ty + r];
    }
    // per-i min over this block's 32 o's: thread t covers i_local=t&31,
    // o_locals = (t>>5)*4 .. +3  (uint-bit min valid: r2 >= 0)
    const int il = t & 31;
    const int g  = t >> 5;
    float mn = fminf(fminf(tile[4 * g + 0][il], tile[4 * g + 1][il]),
                     fminf(tile[4 * g + 2][il], tile[4 * g + 3][il]));
    atomicMin(&mloc[il], __builtin_bit_cast(unsigned, mn));
    __syncthreads();
    if (t < 32) minpart[(size_t)(i0 + t) * NOB + blockIdx.y] = mloc[t];
}

// ---------------------------------------------------------------------------
// Kernel 2: wave owns chunk of 16 i's; lane owns 16 o's. This is the R1 body
// verbatim (fastest measured: 41.6 us) with R4's minpart prologue replacing
// the atomicMin/memset path. Plain v2f math — ISel lowers it to v_pk_*_f32
// on gfx950 (packed-fp32 is on for gfx90a+); hand-written VOP3P asm broke
// numerics in R5 and is banned. Ping-pong row prefetch: the only prefetch
// form the allocator tolerates (R1/R4-verified). No min-waves bound (R2:
// forcing 8/EU spilled catastrophically; live set needs ~70 VGPRs).
// ---------------------------------------------------------------------------
__global__ __launch_bounds__(256) void aeg_main_kernel(
    const float* __restrict__ data,   // (B, I)
    const float* __restrict__ Tt2,    // (I, O) transposed T^2
    const float* __restrict__ minpart,// (I, NOB) min partials (float bits)
    float* __restrict__ out)          // (B, O), zeroed by build_T2
{
    __shared__ float red[WPB][O_];    // 16 KB

    const int w    = threadIdx.x >> 6;
    const int lane = threadIdx.x & 63;
    const int chunk = blockIdx.x * WPB + w;
    const int b     = blockIdx.y;

    const float4* rowbase = (const float4*)(Tt2 + (size_t)chunk * CI * O_);

    // ---- prologue ----
    const int li = lane & 15;                       // lanes 16..63 duplicate

    // exact min over the 32 o-block partials for i = chunk*CI + li
    const float4* mp4 = (const float4*)(minpart + (size_t)(chunk * CI + li) * NOB);
    float4 m0 = mp4[0], m1 = mp4[1], m2_ = mp4[2], m3 = mp4[3];
    float4 m4 = mp4[4], m5 = mp4[5], m6 = mp4[6], m7 = mp4[7];
    float mra = fminf(
        fminf(fminf(fminf(m0.x, m0.y), fminf(m0.z, m0.w)),
              fminf(fminf(m1.x, m1.y), fminf(m1.z, m1.w))),
        fminf(fminf(fminf(m2_.x, m2_.y), fminf(m2_.z, m2_.w)),
              fminf(fminf(m3.x, m3.y), fminf(m3.z, m3.w))));
    float mrb = fminf(
        fminf(fminf(fminf(m4.x, m4.y), fminf(m4.z, m4.w)),
              fminf(fminf(m5.x, m5.y), fminf(m5.z, m5.w))),
        fminf(fminf(fminf(m6.x, m6.y), fminf(m6.z, m6.w)),
              fminf(fminf(m7.x, m7.y), fminf(m7.z, m7.w))));
    const float mr_l = fminf(mra, mrb);

    // per-i sigmoid-derived values; lane j holds i = chunk*CI + j
    const float dv_l  = data[b * I_ + chunk * CI + li];
    const float sig_l = fast_rcp(1.0f + fast_exp2(-dv_l * LOG2E_F));
    const float sc_l  = sig_l * LN2_F;
    const float s2_l  = sc_l * sc_l;
    const float m2_l  = fast_rsq(fmaf(mr_l, s2_l, EPSC_F)); // exact max (log2 units)

    float sdv[CI], ss2[CI], sm2[CI];
#pragma unroll
    for (int j = 0; j < CI; ++j) {
        sdv[j] = readlane_f(dv_l, j);
        ss2[j] = readlane_f(s2_l, j);
        sm2[j] = readlane_f(m2_l, j);
    }

    v2f acc2[8];
#pragma unroll
    for (int j = 0; j < 8; ++j) acc2[j] = (v2f)0.0f;

    float4 rr[2][4];
#pragma unroll
    for (int k = 0; k < 4; ++k) rr[0][k] = rowbase[lane + 64 * k];

#pragma unroll
    for (int ii = 0; ii < CI; ++ii) {
        if (ii + 1 < CI) {
            const float4* nrow = rowbase + (size_t)(ii + 1) * (O_ / 4);
#pragma unroll
            for (int k = 0; k < 4; ++k) rr[(ii + 1) & 1][k] = nrow[lane + 64 * k];
        }
        const float4* r = rr[ii & 1];
        const v2f s2v = {ss2[ii], ss2[ii]};
        const v2f m2v = {sm2[ii], sm2[ii]};
        const v2f epv = {EPSC_F, EPSC_F};

        v2f e2[8];
        v2f zv0 = (v2f)0.0f, zv1 = (v2f)0.0f;
#pragma unroll
        for (int k = 0; k < 4; ++k) {
            const v2f a = {r[k].x, r[k].y};
            const v2f c = {r[k].z, r[k].w};
            const v2f q0 = a * s2v + epv;
            const v2f q1 = c * s2v + epv;
            v2f t0, t1;
            t0.x = fast_rsq(q0.x); t0.y = fast_rsq(q0.y);
            t1.x = fast_rsq(q1.x); t1.y = fast_rsq(q1.y);
            t0 -= m2v;
            t1 -= m2v;
            v2f ev0, ev1;
            ev0.x = fast_exp2(t0.x); ev0.y = fast_exp2(t0.y);
            ev1.x = fast_exp2(t1.x); ev1.y = fast_exp2(t1.y);
            e2[2 * k]     = ev0;
            e2[2 * k + 1] = ev1;
            zv0 += ev0;
            zv1 += ev1;
        }
        const v2f zv = zv0 + zv1;
        const float zt = wave_sum_uniform(zv.x + zv.y);    // SGPR-uniform
        const float scale = sdv[ii] * fast_rcp(zt);        // z >= 1 (max term = 1)
        const v2f sc2 = {scale, scale};
#pragma unroll
        for (int j = 0; j < 8; ++j)
            acc2[j] = e2[j] * sc2 + acc2[j];
    }

    // Stage per-wave accumulators, reduce across the 4 waves in LDS.
#pragma unroll
    for (int k = 0; k < 4; ++k) {
        float4 v;
        v.x = acc2[2 * k].x;     v.y = acc2[2 * k].y;
        v.z = acc2[2 * k + 1].x; v.w = acc2[2 * k + 1].y;
        ((float4*)&red[w][256 * k])[lane] = v;
    }
    __syncthreads();

    const int t = threadIdx.x;
    float4 v = ((const float4*)red[0])[t];
#pragma unroll
    for (int ww = 1; ww < WPB; ++ww) {
        const float4 u = ((const float4*)red[ww])[t];
        v.x += u.x; v.y += u.y; v.z += u.z; v.w += u.w;
    }
    float* ob = out + b * O_ + 4 * t;
    atomicAdd(&ob[0], v.x);
    atomicAdd(&ob[1], v.y);
    atomicAdd(&ob[2], v.z);
    atomicAdd(&ob[3], v.w);
}

// ---------------------------------------------------------------------------
extern "C" void kernel_launch(void* const* d_in, const int* in_sizes, int n_in,
                              void* d_out, int out_size, void* d_ws, size_t ws_size,
                              hipStream_t stream)
{
    const float* data = (const float*)d_in[0];
    const float* ix   = (const float*)d_in[1];
    const float* iy   = (const float*)d_in[2];
    const float* ox   = (const float*)d_in[3];
    const float* oy   = (const float*)d_in[4];
    const float* la   = (const float*)d_in[5];
    const float* lm   = (const float*)d_in[6];
    float* out  = (float*)d_out;
    float* Tt2  = (float*)d_ws;
    unsigned* minpart = (unsigned*)((char*)d_ws + TT_BYTES);

    build_T2_kernel<<<dim3(I_ / 32, O_ / 32), dim3(32, 8), 0, stream>>>(
        ix, iy, ox, oy, la, lm, Tt2, minpart, out);

    aeg_main_kernel<<<dim3(NCHUNK / WPB, B_), 256, 0, stream>>>(
        data, Tt2, (const float*)minpart, out);
}